// Round 2
// baseline (161.713 us; speedup 1.0000x reference)
//
#include <hip/hip_runtime.h>
#include <hip/hip_bf16.h>
#include <stdint.h>

typedef __attribute__((ext_vector_type(8))) short short8;
typedef __attribute__((ext_vector_type(4))) float f32x4;

#define NCHUNK 15625   // 500000 / 32 rows per chunk (exact)
#define NBLK 256
#define NTHR 512
#define NWAVE_TOT (NBLK * 8)

// round-to-nearest-even fp32 -> bf16 bits
__device__ __forceinline__ unsigned short f2bf(float f) {
    unsigned int u = __float_as_uint(f);
    u = (u + 0x7fffu + ((u >> 16) & 1u)) >> 16;
    return (unsigned short)u;
}

// Pack W2 into mfma_f32_16x16x32_bf16 B-fragment order:
//   frag f = s*16 + t  (s = k-step 0..7, t = n-tile 0..15)
//   lane l holds B[k = s*32 + (l>>4)*8 + j][n = t*16 + (l&15)], j = 0..7
//   stored as 16 bytes per lane, frags contiguous: w2p[(f*64 + l)] (uint4)
// Also pack W1+b1 -> [256] float4 {W1[0][k],W1[1][k],W1[2][k],b1[k]}
// and  W3+b2 -> [256] float4 {W3[c][0],W3[c][1],W3[c][2],b2[c]}
__global__ void prep_kernel(const float* __restrict__ W1, const float* __restrict__ b1,
                            const float* __restrict__ W2, const float* __restrict__ b2,
                            const float* __restrict__ W3,
                            uint4* __restrict__ w2p, float4* __restrict__ w1b1,
                            float4* __restrict__ w3b2) {
    int id = blockIdx.x * 256 + threadIdx.x;
    if (id < 8192) {
        int lane = id & 63;
        int f = id >> 6;
        int s = f >> 4, t = f & 15;
        int g = lane >> 4, c = lane & 15;
        int n = t * 16 + c;
        int kbase = s * 32 + g * 8;
        unsigned int w[4];
#pragma unroll
        for (int jj = 0; jj < 4; ++jj) {
            unsigned int lo = f2bf(W2[(kbase + 2 * jj) * 256 + n]);
            unsigned int hi = f2bf(W2[(kbase + 2 * jj + 1) * 256 + n]);
            w[jj] = lo | (hi << 16);
        }
        w2p[id] = make_uint4(w[0], w[1], w[2], w[3]);
    } else if (id < 8448) {
        int k = id - 8192;
        w1b1[k] = make_float4(W1[k], W1[256 + k], W1[512 + k], b1[k]);
    } else if (id < 8704) {
        int c2 = id - 8448;
        w3b2[c2] = make_float4(W3[c2 * 3 + 0], W3[c2 * 3 + 1], W3[c2 * 3 + 2], b2[c2]);
    }
}

__global__ __launch_bounds__(NTHR, 2) void fused_kernel(
    const float* __restrict__ x, const uint4* __restrict__ w2p,
    const float4* __restrict__ w1b1, const float4* __restrict__ w3b2,
    const float* __restrict__ b3, float* __restrict__ out)
{
    extern __shared__ char smem[];   // 128 KB: W2 B-fragments (bf16)
    const int tid = threadIdx.x;
    const int lane = tid & 63;
    const int g = lane >> 4;         // k-group within fragment
    const int lr = lane & 15;        // A-row / C-col within tile

    // one-time stage of packed W2 into LDS (reg-staged copy, 16B per thread per iter)
    {
        uint4* ls = (uint4*)smem;
#pragma unroll
        for (int it = 0; it < 16; ++it) {
            int idx = it * NTHR + tid;        // 16*512 = 8192 uint4 = 128 KB
            ls[idx] = w2p[idx];
        }
    }
    __syncthreads();
    // after this point waves are fully independent (LDS is read-only)

    const float b30 = b3[0], b31 = b3[1], b32 = b3[2];
    const short8* bfr = (const short8*)smem;
    const int gwave = blockIdx.x * 8 + (tid >> 6);

    for (int chunk = gwave; chunk < NCHUNK; chunk += NWAVE_TOT) {
        const int row0 = chunk * 32;

        // ---- bond lengths for this lane's rows (row = l&15 of each 16-row M-tile) ----
        float q0[2], q1[2], q2[2];
#pragma unroll
        for (int mt = 0; mt < 2; ++mt) {
            const float* xp = x + (long)(row0 + mt * 16 + lr) * 9;
            float d0 = xp[0] - xp[3], d1 = xp[1] - xp[4], d2 = xp[2] - xp[5];
            float e0 = xp[0] - xp[6], e1 = xp[1] - xp[7], e2 = xp[2] - xp[8];
            float f0 = xp[3] - xp[6], f1 = xp[4] - xp[7], f2 = xp[5] - xp[8];
            q0[mt] = sqrtf(d0 * d0 + d1 * d1 + d2 * d2);   // pair (0,1)
            q1[mt] = sqrtf(e0 * e0 + e1 * e1 + e2 * e2);   // pair (0,2)
            q2[mt] = sqrtf(f0 * f0 + f1 * f1 + f2 * f2);   // pair (1,2)
        }

        // ---- layer 2 accumulators ----
        f32x4 acc[2][16];
        const f32x4 zz = {0.0f, 0.0f, 0.0f, 0.0f};
#pragma unroll
        for (int t = 0; t < 16; ++t) { acc[0][t] = zz; acc[1][t] = zz; }

        // ---- K loop: build A-fragments (layer 1) on the fly, MFMA vs LDS B-frags ----
#pragma unroll 1
        for (int s = 0; s < 8; ++s) {
            short8 a0v, a1v;
#pragma unroll
            for (int j = 0; j < 8; ++j) {
                float4 wb = w1b1[s * 32 + g * 8 + j];   // {W1_0, W1_1, W1_2, b1} for k
                float h0 = fmaf(q0[0], wb.x, fmaf(q1[0], wb.y, fmaf(q2[0], wb.z, wb.w)));
                float h1 = fmaf(q0[1], wb.x, fmaf(q1[1], wb.y, fmaf(q2[1], wb.z, wb.w)));
                a0v[j] = (short)f2bf(fmaxf(h0, 0.0f));
                a1v[j] = (short)f2bf(fmaxf(h1, 0.0f));
            }
#pragma unroll
            for (int t = 0; t < 16; ++t) {
                short8 bv = bfr[(s * 16 + t) * 64 + lane];
                acc[0][t] = __builtin_amdgcn_mfma_f32_16x16x32_bf16(a0v, bv, acc[0][t], 0, 0, 0);
                acc[1][t] = __builtin_amdgcn_mfma_f32_16x16x32_bf16(a1v, bv, acc[1][t], 0, 0, 0);
            }
        }

        // ---- layer 3: per-lane partial dot over its 16 columns, fp32 ----
        // C/D layout: lane holds h2[row=(g*4 + r)][col=t*16 + lr] in acc[mt][t][r]
        float p[2][4][3];
#pragma unroll
        for (int mt = 0; mt < 2; ++mt)
#pragma unroll
            for (int r = 0; r < 4; ++r) { p[mt][r][0] = 0.f; p[mt][r][1] = 0.f; p[mt][r][2] = 0.f; }

#pragma unroll
        for (int t = 0; t < 16; ++t) {
            float4 wb = w3b2[t * 16 + lr];   // {W3_0, W3_1, W3_2, b2} for col c
#pragma unroll
            for (int mt = 0; mt < 2; ++mt)
#pragma unroll
                for (int r = 0; r < 4; ++r) {
                    float v = fmaxf(acc[mt][t][r] + wb.w, 0.0f);
                    p[mt][r][0] = fmaf(v, wb.x, p[mt][r][0]);
                    p[mt][r][1] = fmaf(v, wb.y, p[mt][r][1]);
                    p[mt][r][2] = fmaf(v, wb.z, p[mt][r][2]);
                }
        }

        // ---- butterfly reduce over the 16 lanes of each k-group ----
#pragma unroll
        for (int mt = 0; mt < 2; ++mt)
#pragma unroll
            for (int r = 0; r < 4; ++r)
#pragma unroll
                for (int m = 0; m < 3; ++m) {
                    float v = p[mt][r][m];
                    v += __shfl_xor(v, 1, 16);
                    v += __shfl_xor(v, 2, 16);
                    v += __shfl_xor(v, 4, 16);
                    v += __shfl_xor(v, 8, 16);
                    p[mt][r][m] = v;
                }

        // ---- eigenvalues + store (lane lr==0 of each group owns rows g*4 .. g*4+3) ----
        if (lr == 0) {
#pragma unroll
            for (int mt = 0; mt < 2; ++mt)
#pragma unroll
                for (int r = 0; r < 4; ++r) {
                    float w0 = p[mt][r][0] + b30;
                    float w1v = p[mt][r][1] + b31;
                    float w2v = p[mt][r][2] + b32;
                    float mm = 0.5f * (w0 + w1v);
                    float dd = 0.5f * (w0 - w1v);
                    float rad = sqrtf(fmaf(dd, dd, w2v * w2v));
                    int row = row0 + mt * 16 + g * 4 + r;
                    float2 o = make_float2(mm - rad, mm + rad);
                    *(float2*)(out + (long)row * 2) = o;
                }
        }
    }
}

extern "C" void kernel_launch(void* const* d_in, const int* in_sizes, int n_in,
                              void* d_out, int out_size, void* d_ws, size_t ws_size,
                              hipStream_t stream) {
    const float* x  = (const float*)d_in[0];
    const float* W1 = (const float*)d_in[1];
    const float* b1 = (const float*)d_in[2];
    const float* W2 = (const float*)d_in[3];
    const float* b2 = (const float*)d_in[4];
    const float* W3 = (const float*)d_in[5];
    const float* b3 = (const float*)d_in[6];
    float* out = (float*)d_out;

    char* ws = (char*)d_ws;
    uint4*  w2p  = (uint4*)ws;                 // 131072 B: packed bf16 W2 fragments
    float4* w1b1 = (float4*)(ws + 131072);     // 4096 B
    float4* w3b2 = (float4*)(ws + 135168);     // 4096 B

    // allow 128 KB dynamic LDS (not a stream op; capture-safe)
    (void)hipFuncSetAttribute((const void*)fused_kernel,
                              hipFuncAttributeMaxDynamicSharedMemorySize, 131072);

    prep_kernel<<<34, 256, 0, stream>>>(W1, b1, W2, b2, W3, w2p, w1b1, w3b2);
    fused_kernel<<<NBLK, NTHR, 131072, stream>>>(x, w2p, w1b1, w3b2, b3, out);
}